// Round 1
// baseline (1176.607 us; speedup 1.0000x reference)
//
#include <hip/hip_runtime.h>
#include <cstdint>
#include <cstddef>

// W8A8LinearStatic: out[m][n] = (sum_k round(x[m][k]/s_act) * W[n][k]) * out_scales[n]
// M=8192 (B*S), N=11008, K=4096. fp16 GEMM (exact: |q_x|<2048 integer, |W|<=127).
//
// R3: 256x256 8-phase schedule (T3+T4 counted vmcnt + T5 setprio), ported from the
// verified gemm_256sq_8phase template. 512 threads = 8 waves (2Mx4N), 128 KiB
// double-buffered LDS, XOR-swizzled reads with pre-swizzled global_load_lds source,
// XCD-bijective tile order (1376 = 8*172), nontemporal epilogue stores.

#define M_DIM 8192
#define N_DIM 11008
#define K_DIM 4096

// ---- main 256x256 kernel geometry ----
#define G_TM 32                 // M/256
#define G_TN 43                 // N/256
#define G_NB (G_TM * G_TN)      // 1376 = 8 XCDs * 172
#define NT   (K_DIM / 64)       // 64 K-tiles of BK=64

// ---- fallback kernel geometry (128x128, prior verified path) ----
#define FB_TM 64
#define FB_TN 86
#define FB_NB (FB_TM * FB_TN)   // 5504
#define FB_GROUP 16

typedef _Float16 half8 __attribute__((ext_vector_type(8)));
typedef float    f32x4 __attribute__((ext_vector_type(4)));

#define GLOBAL_AS(p) ((const __attribute__((address_space(1))) void*)(p))
#define LDS_AS(p)    ((__attribute__((address_space(3))) void*)(p))

#define MFMA16(a,b,c) __builtin_amdgcn_mfma_f32_16x16x32_f16((a),(b),(c),0,0,0)

// raw s_barrier (no vmcnt drain!) with compiler memory fences so LDS ops can't
// be moved across it; the hardware waitcnts are issued explicitly.
#define BARRIER() do { asm volatile("" ::: "memory"); \
                       __builtin_amdgcn_s_barrier();  \
                       asm volatile("" ::: "memory"); } while (0)

// ---------------- quantize activations: q = rint(x * (1/s)), store fp16 ----------------
__global__ __launch_bounds__(256) void quant_x_kernel(
    const float* __restrict__ x, const float* __restrict__ act_s,
    _Float16* __restrict__ qx)
{
    const float inv = 1.0f / act_s[0];
    size_t idx = ((size_t)blockIdx.x * 256u + threadIdx.x) * 8u;
    const float4* p = (const float4*)(x + idx);
    float4 v0 = p[0];
    float4 v1 = p[1];
    half8 h;
    h[0] = (_Float16)rintf(v0.x * inv);
    h[1] = (_Float16)rintf(v0.y * inv);
    h[2] = (_Float16)rintf(v0.z * inv);
    h[3] = (_Float16)rintf(v0.w * inv);
    h[4] = (_Float16)rintf(v1.x * inv);
    h[5] = (_Float16)rintf(v1.y * inv);
    h[6] = (_Float16)rintf(v1.z * inv);
    h[7] = (_Float16)rintf(v1.w * inv);
    *(half8*)(qx + idx) = h;
}

// ---------------- convert weights: int32 (int8-valued) -> fp16 ----------------
__global__ __launch_bounds__(256) void quant_w_kernel(
    const int* __restrict__ w, _Float16* __restrict__ qw)
{
    size_t idx = ((size_t)blockIdx.x * 256u + threadIdx.x) * 8u;
    const int4* p = (const int4*)(w + idx);
    int4 v0 = p[0];
    int4 v1 = p[1];
    half8 h;
    h[0] = (_Float16)v0.x;
    h[1] = (_Float16)v0.y;
    h[2] = (_Float16)v0.z;
    h[3] = (_Float16)v0.w;
    h[4] = (_Float16)v1.x;
    h[5] = (_Float16)v1.y;
    h[6] = (_Float16)v1.z;
    h[7] = (_Float16)v1.w;
    *(half8*)(qw + idx) = h;
}

// ---------------- staging: one 128-row half-tile (2 x global_load_lds 16B) ----------
// LDS layout per operand buffer: 256 rows x 8 kchunks of 16B, linear write
// slot(row,kcs) = row*64 + kcs*8 halves; stored chunk kcs holds GLOBAL chunk
// kcs ^ (row&7) (source pre-swizzle; read applies the same XOR -> involution).
// src already includes (row0 + tid>>3)*K + ((tid&7)^((tid>>3)&7))*8.
// lds already includes buf base + tid*8.
__device__ __forceinline__ void stage_half(const _Float16* __restrict__ src,
                                           _Float16* lds, int koff, int hrow)
{
    const _Float16* s = src + (size_t)hrow * K_DIM + koff;
    __builtin_amdgcn_global_load_lds(GLOBAL_AS(s),
        LDS_AS(lds + hrow * 64), 16, 0, 0);
    __builtin_amdgcn_global_load_lds(GLOBAL_AS(s + (size_t)64 * K_DIM),
        LDS_AS(lds + hrow * 64 + 4096), 16, 0, 0);
}

// ---------------- one K-tile window = 4 phases ----------------
// SM: 2 = steady state (stage t+1 halves + (t+2,AH0), vmcnt(2))
//     1 = t == NT-2   (stage t+1 halves only, vmcnt(0))
//     0 = t == NT-1   (no staging, no wait)
// Staging stream (1 half-tile per phase): ph0:(t+1,AH1) ph1:(t+1,BH0)
// ph2:(t+1,BH1) ph3:(t+2,AH0).   (t+1,AH0) was staged at W(t-1).ph3.
// Hazard proof: a buffer's ds_reads finish (block-wide) at that phase's
// trailing barrier; every overwrite above is issued >= 1 barrier later.
template<int SM>
__device__ __forceinline__ void gemm_window(
    const _Float16* __restrict__ aSrc, const _Float16* __restrict__ bSrc,
    int koff,
    const _Float16* aT, const _Float16* bT,   // current LDS buffers
    _Float16* aN, _Float16* bN,               // next buffers (+ tid*8)
    _Float16* aC,                             // current A buffer (+ tid*8), for (t+2,AH0)
    int aRowBase, int bRowBase, int q4, int xm,
    f32x4 (&acc)[8][4])
{
    const int c0 = (q4 ^ xm) * 8;             // ks=0 swizzled chunk offset (halves)
    const int c1 = ((4 + q4) ^ xm) * 8;       // ks=1

    half8 af[4][2], bf0[2][2], bf1[2][2];

    // ---- phase 0: read A row-half0 + B col-half0; stage (t+1, AH1); quad (0,0) ----
#pragma unroll
    for (int fr = 0; fr < 4; ++fr) {
        af[fr][0] = *(const half8*)(aT + aRowBase + fr * 1024 + c0);
        af[fr][1] = *(const half8*)(aT + aRowBase + fr * 1024 + c1);
    }
#pragma unroll
    for (int fc = 0; fc < 2; ++fc) {
        bf0[fc][0] = *(const half8*)(bT + bRowBase + fc * 1024 + c0);
        bf0[fc][1] = *(const half8*)(bT + bRowBase + fc * 1024 + c1);
    }
    if (SM >= 1) stage_half(aSrc, aN, koff + 64, 128);
    asm volatile("s_waitcnt lgkmcnt(8)" ::: "memory");   // 12 ds_reads issued
    BARRIER();
    asm volatile("s_waitcnt lgkmcnt(0)" ::: "memory");
    __builtin_amdgcn_s_setprio(1);
#pragma unroll
    for (int fr = 0; fr < 4; ++fr)
#pragma unroll
        for (int fc = 0; fc < 2; ++fc) {
            acc[fr][fc] = MFMA16(af[fr][0], bf0[fc][0], acc[fr][fc]);
            acc[fr][fc] = MFMA16(af[fr][1], bf0[fc][1], acc[fr][fc]);
        }
    __builtin_amdgcn_s_setprio(0);
    BARRIER();

    // ---- phase 1: read B col-half1; stage (t+1, BH0); quad (0,1) ----
#pragma unroll
    for (int fc = 0; fc < 2; ++fc) {
        bf1[fc][0] = *(const half8*)(bT + bRowBase + 2048 + fc * 1024 + c0);
        bf1[fc][1] = *(const half8*)(bT + bRowBase + 2048 + fc * 1024 + c1);
    }
    if (SM >= 1) stage_half(bSrc, bN, koff + 64, 0);
    BARRIER();
    asm volatile("s_waitcnt lgkmcnt(0)" ::: "memory");
    __builtin_amdgcn_s_setprio(1);
#pragma unroll
    for (int fr = 0; fr < 4; ++fr)
#pragma unroll
        for (int fc = 0; fc < 2; ++fc) {
            acc[fr][2 + fc] = MFMA16(af[fr][0], bf1[fc][0], acc[fr][2 + fc]);
            acc[fr][2 + fc] = MFMA16(af[fr][1], bf1[fc][1], acc[fr][2 + fc]);
        }
    __builtin_amdgcn_s_setprio(0);
    BARRIER();

    // ---- phase 2: read A row-half1 (reuse af regs); stage (t+1, BH1); quad (1,1) ----
#pragma unroll
    for (int fr = 0; fr < 4; ++fr) {
        af[fr][0] = *(const half8*)(aT + aRowBase + 4096 + fr * 1024 + c0);
        af[fr][1] = *(const half8*)(aT + aRowBase + 4096 + fr * 1024 + c1);
    }
    if (SM >= 1) stage_half(bSrc, bN, koff + 64, 128);
    BARRIER();
    asm volatile("s_waitcnt lgkmcnt(0)" ::: "memory");
    __builtin_amdgcn_s_setprio(1);
#pragma unroll
    for (int fr = 0; fr < 4; ++fr)
#pragma unroll
        for (int fc = 0; fc < 2; ++fc) {
            acc[4 + fr][2 + fc] = MFMA16(af[fr][0], bf1[fc][0], acc[4 + fr][2 + fc]);
            acc[4 + fr][2 + fc] = MFMA16(af[fr][1], bf1[fc][1], acc[4 + fr][2 + fc]);
        }
    __builtin_amdgcn_s_setprio(0);
    BARRIER();

    // ---- phase 3: stage (t+2, AH0) into current A buffer; quad (1,0); counted vmcnt ----
    if (SM == 2) stage_half(aSrc, aC, koff + 128, 0);
    BARRIER();
    __builtin_amdgcn_s_setprio(1);
#pragma unroll
    for (int fr = 0; fr < 4; ++fr)
#pragma unroll
        for (int fc = 0; fc < 2; ++fc) {
            acc[4 + fr][fc] = MFMA16(af[fr][0], bf0[fc][0], acc[4 + fr][fc]);
            acc[4 + fr][fc] = MFMA16(af[fr][1], bf0[fc][1], acc[4 + fr][fc]);
        }
    __builtin_amdgcn_s_setprio(0);
    // drain everything except the newest half-tile ((t+2,AH0): 2 loads) -> the
    // (t+1) K-tile is complete before the next window's phase-0 ds_reads.
    if (SM == 2)      asm volatile("s_waitcnt vmcnt(2)" ::: "memory");
    else if (SM == 1) asm volatile("s_waitcnt vmcnt(0)" ::: "memory");
    BARRIER();
}

// ---------------- main GEMM: 256x256 tile, 8 waves, 8-phase pipeline ----------------
__global__ __launch_bounds__(512, 2) void w8a8_gemm256(
    const _Float16* __restrict__ Aq, const _Float16* __restrict__ Bq,
    const float* __restrict__ out_s, float* __restrict__ out)
{
    __shared__ _Float16 As[2 * 256 * 64];   // 64 KiB (double-buffered A tile)
    __shared__ _Float16 Bs[2 * 256 * 64];   // 64 KiB

    const int tid  = threadIdx.x;
    const int lane = tid & 63;
    const int wv   = tid >> 6;          // 0..7
    const int wm   = wv >> 2;           // 0..1  (wave row)
    const int wn   = wv & 3;            // 0..3  (wave col)
    const int m16  = lane & 15;
    const int q4   = lane >> 4;         // 0..3
    const int xm   = m16 & 7;

    // XCD-bijective tile map: 1376 blocks = 8 XCDs x 172. XCD x (= id&7) owns
    // tile-rows 4x..4x+3, walked column-major -> 4 consecutive same-XCD blocks
    // share one B panel; full A+B working set (150 MiB) stays L3-resident.
    const int id = blockIdx.x;
    const int tn = id >> 5;                              // 0..42
    const int tm = ((id & 7) << 2) | ((id >> 3) & 3);    // 0..31

    const int row0 = tm * 256;
    const int col0 = tn * 256;

    // staging source: pre-swizzled global chunk (rule #21: linear LDS dest,
    // inverse-swizzled source, swizzled read; XOR with row&7 is an involution)
    const int srow6  = tid >> 3;                    // 0..63
    const int gchunk = (tid & 7) ^ (srow6 & 7);

    const _Float16* aSrc = Aq + (size_t)(row0 + srow6) * K_DIM + gchunk * 8;
    const _Float16* bSrc = Bq + (size_t)(col0 + srow6) * K_DIM + gchunk * 8;

    _Float16* aL0 = As + tid * 8;
    _Float16* aL1 = As + 16384 + tid * 8;
    _Float16* bL0 = Bs + tid * 8;
    _Float16* bL1 = Bs + 16384 + tid * 8;

    const int aRowBase = wm * 8192 + m16 * 64;      // (wm*128 + m16) * 64
    const int bRowBase = wn * 4096 + m16 * 64;      // (wn*64  + m16) * 64

    f32x4 acc[8][4];
#pragma unroll
    for (int i = 0; i < 8; ++i)
#pragma unroll
        for (int j = 0; j < 4; ++j)
            acc[i][j] = (f32x4)0.0f;

    // prologue: K-tile 0 complete (4 half-tiles) + (K-tile 1, AH0); then allow
    // the newest 2 loads ((1,AH0)) to stay in flight.
    stage_half(aSrc, aL0, 0, 0);      // (0, AH0)
    stage_half(aSrc, aL0, 0, 128);    // (0, AH1)
    stage_half(bSrc, bL0, 0, 0);      // (0, BH0)
    stage_half(bSrc, bL0, 0, 128);    // (0, BH1)
    stage_half(aSrc, aL1, 64, 0);     // (1, AH0)
    asm volatile("s_waitcnt vmcnt(2)" ::: "memory");
    BARRIER();

    // main loop: 2 K-tile windows per iteration (buf0 then buf1)
    for (int tt = 0; tt < 31; ++tt) {
        const int k0 = tt << 7;       // t*64 halves, t = 2*tt
        gemm_window<2>(aSrc, bSrc, k0,
                       As, Bs, aL1, bL1, aL0, aRowBase, bRowBase, q4, xm, acc);
        gemm_window<2>(aSrc, bSrc, k0 + 64,
                       As + 16384, Bs + 16384, aL0, bL0, aL1, aRowBase, bRowBase, q4, xm, acc);
    }
    // t = 62: stage K-tile 63's remaining halves, full drain
    gemm_window<1>(aSrc, bSrc, 62 * 64,
                   As, Bs, aL1, bL1, aL0, aRowBase, bRowBase, q4, xm, acc);
    // t = 63: compute only
    gemm_window<0>(aSrc, bSrc, 63 * 64,
                   As + 16384, Bs + 16384, aL0, bL0, aL1, aRowBase, bRowBase, q4, xm, acc);

    // epilogue: D mapping col(n) = lane&15, row(m) = (lane>>4)*4 + reg.
    // Nontemporal: the 360MB output stream must not evict A/B panels from L2/L3.
    const int orow0 = row0 + wm * 128 + q4 * 4;
    const int ocol  = col0 + wn * 64 + m16;
#pragma unroll
    for (int fc = 0; fc < 4; ++fc) {
        const int n = ocol + fc * 16;
        const float sc = out_s[n];
#pragma unroll
        for (int fr = 0; fr < 8; ++fr) {
            const int r0 = orow0 + fr * 16;
#pragma unroll
            for (int rg = 0; rg < 4; ++rg)
                __builtin_nontemporal_store(acc[fr][fc][rg] * sc,
                    out + (size_t)(r0 + rg) * N_DIM + n);
        }
    }
}

// ---------------- fallback (ws too small): prior verified 128x128 path ----------------
__global__ __launch_bounds__(256, 2) void w8a8_gemm_fb(
    const float* __restrict__ X, const int* __restrict__ Wt,
    const float* __restrict__ act_s, const float* __restrict__ out_s,
    float* __restrict__ out)
{
    __shared__ _Float16 As[128 * 64];
    __shared__ _Float16 Bs[128 * 64];

    const int tid  = threadIdx.x;
    const int lane = tid & 63;
    const int wv   = tid >> 6;
    const int wrow = (wv >> 1) * 64;
    const int wcol = (wv & 1) * 64;
    const int m16  = lane & 15;
    const int q4   = lane >> 4;
    const int xm   = m16 & 7;

    const int id   = blockIdx.x;
    const int gid  = (id & 7) * (FB_NB / 8) + (id >> 3);
    const int gsz  = FB_GROUP * FB_TN;
    const int grp  = gid / gsz;
    const int rem  = gid - grp * gsz;
    const int tn   = rem / FB_GROUP;
    const int tm   = grp * FB_GROUP + (rem - tn * FB_GROUP);

    const int row0 = tm * 128;
    const int col0 = tn * 128;

    const int srow = tid >> 3;
    const int sj   = (tid & 7) ^ (srow & 7);

    f32x4 acc[4][4];
#pragma unroll
    for (int i = 0; i < 4; ++i)
#pragma unroll
        for (int j = 0; j < 4; ++j)
            acc[i][j] = (f32x4)0.0f;

    const float inv = 1.0f / act_s[0];
    const float* xSrc = X  + (size_t)(row0 + srow) * K_DIM + sj * 8;
    const int*   wSrc = Wt + (size_t)(col0 + srow) * K_DIM + sj * 8;

    _Float16* aDst = As + tid * 8;
    _Float16* bDst = Bs + tid * 8;

    for (int kk = 0; kk < K_DIM / 64; ++kk) {
#pragma unroll
        for (int i = 0; i < 4; ++i) {
            const float4* p = (const float4*)(xSrc + (size_t)i * 32 * K_DIM);
            float4 v0 = p[0];
            float4 v1 = p[1];
            half8 h;
            h[0] = (_Float16)rintf(v0.x * inv);
            h[1] = (_Float16)rintf(v0.y * inv);
            h[2] = (_Float16)rintf(v0.z * inv);
            h[3] = (_Float16)rintf(v0.w * inv);
            h[4] = (_Float16)rintf(v1.x * inv);
            h[5] = (_Float16)rintf(v1.y * inv);
            h[6] = (_Float16)rintf(v1.z * inv);
            h[7] = (_Float16)rintf(v1.w * inv);
            *(half8*)(aDst + i * 256 * 8) = h;
        }
#pragma unroll
        for (int i = 0; i < 4; ++i) {
            const int4* p = (const int4*)(wSrc + (size_t)i * 32 * K_DIM);
            int4 v0 = p[0];
            int4 v1 = p[1];
            half8 h;
            h[0] = (_Float16)v0.x;
            h[1] = (_Float16)v0.y;
            h[2] = (_Float16)v0.z;
            h[3] = (_Float16)v0.w;
            h[4] = (_Float16)v1.x;
            h[5] = (_Float16)v1.y;
            h[6] = (_Float16)v1.z;
            h[7] = (_Float16)v1.w;
            *(half8*)(bDst + i * 256 * 8) = h;
        }
        xSrc += 64;
        wSrc += 64;

        __syncthreads();

#pragma unroll
        for (int s = 0; s < 2; ++s) {
            half8 af[4], bf[4];
            const int chunk = (s * 4 + q4) ^ xm;
#pragma unroll
            for (int t = 0; t < 4; ++t) {
                af[t] = *(const half8*)(As + (wrow + t * 16 + m16) * 64 + chunk * 8);
                bf[t] = *(const half8*)(Bs + (wcol + t * 16 + m16) * 64 + chunk * 8);
            }
#pragma unroll
            for (int ti = 0; ti < 4; ++ti)
#pragma unroll
                for (int tj = 0; tj < 4; ++tj)
                    acc[ti][tj] = MFMA16(af[ti], bf[tj], acc[ti][tj]);
        }
        __syncthreads();
    }

#pragma unroll
    for (int tj = 0; tj < 4; ++tj) {
        const int n = col0 + wcol + tj * 16 + m16;
        const float sc = out_s[n];
#pragma unroll
        for (int ti = 0; ti < 4; ++ti) {
            const int rbase = row0 + wrow + ti * 16 + q4 * 4;
#pragma unroll
            for (int r = 0; r < 4; ++r) {
                __builtin_nontemporal_store(acc[ti][tj][r] * sc,
                    out + (size_t)(rbase + r) * N_DIM + n);
            }
        }
    }
}

extern "C" void kernel_launch(void* const* d_in, const int* in_sizes, int n_in,
                              void* d_out, int out_size, void* d_ws, size_t ws_size,
                              hipStream_t stream) {
    const float* x     = (const float*)d_in[0];
    const int*   w     = (const int*)d_in[1];
    const float* act_s = (const float*)d_in[2];
    const float* out_s = (const float*)d_in[3];
    float* out = (float*)d_out;

    const size_t bytesA = (size_t)M_DIM * K_DIM * sizeof(_Float16);   // 64 MiB
    const size_t bytesB = (size_t)N_DIM * K_DIM * sizeof(_Float16);   // 86 MiB

    if (ws_size >= bytesA + bytesB) {
        _Float16* Aq = (_Float16*)d_ws;
        _Float16* Bq = (_Float16*)((char*)d_ws + bytesA);
        quant_x_kernel<<<(int)(((size_t)M_DIM * K_DIM) / 2048), 256, 0, stream>>>(x, act_s, Aq);
        quant_w_kernel<<<(int)(((size_t)N_DIM * K_DIM) / 2048), 256, 0, stream>>>(w, Bq);
        w8a8_gemm256<<<G_NB, 512, 0, stream>>>(Aq, Bq, out_s, out);
    } else {
        w8a8_gemm_fb<<<FB_NB, 256, 0, stream>>>(x, w, act_s, out_s, out);
    }
}